// Round 5
// baseline (592.023 us; speedup 1.0000x reference)
//
#include <hip/hip_runtime.h>
#include <math.h>

#define NB 64
#define NS 2048
#define NH 512
#define NE 512
#define NV 50257
#define H3 1536
#define KSL 8          // GRU split-K slices
#define NCH 32         // attention s-chunks per b

typedef __attribute__((ext_vector_type(8))) short bf16x8;
typedef __attribute__((ext_vector_type(4))) float f32x4;

// ---- workspace layout (float offsets) ----
#define GI_OFF    0                            // [8][1536][64] gi split-K partials
#define GH_OFF    (GI_OFF + KSL*H3*NB)         // [8][1536][64]
#define HNEW_OFF  (GH_OFF + KSL*H3*NB)         // [64][512]
#define EN_OFF    (HNEW_OFF + NB*NH)           // [64][2048] raw energies
#define PCTX_OFF  (EN_OFF + NB*NS)             // [64][32][512] partial ctx
#define PM_OFF    (PCTX_OFF + NB*NCH*NH)       // [64][32] partial max
#define PL_OFF    (PM_OFF + NB*NCH)            // [64][32] partial sum
#define CTX_OFF   (PL_OFF + NB*NCH)            // [64][512]
#define CCB_OFF   (CTX_OFF + NB*NH)            // [64][512] concat_output bf16 (ushort)
#define CNT_OFF   (CCB_OFF + NB*NH/2)          // 128 uint counters

// ---- d_out layout (float offsets) ----
#define HID_OFF  ((size_t)NB*NV)
#define ATTN_OFF (HID_OFF + (size_t)NB*NH)

__device__ __forceinline__ unsigned short f2bf(float f) {
    unsigned u = __builtin_bit_cast(unsigned, f);
    u += 0x7FFFu + ((u >> 16) & 1u);   // RNE
    return (unsigned short)(u >> 16);
}

// kA: fused GRU. grid (32 h-tiles, 8 k-slices). Each block computes partial
// gi/gh for rows {h,512+h,1024+h} x 16 h x 64 b over its 64-k slice; the last
// slice block (device atomic) combines + gate math -> h_new + hidden out.
__global__ __launch_bounds__(256) void kA_gru(
    const int* __restrict__ seq, const float* __restrict__ lh,
    const float* __restrict__ emb, const float* __restrict__ wih,
    const float* __restrict__ whh, const float* __restrict__ bih,
    const float* __restrict__ bhh, float* __restrict__ ws,
    float* __restrict__ out, unsigned* __restrict__ cnt)
{
    __shared__ float xl[64][65];
    __shared__ float hl[64][65];
    __shared__ int idxl[64];
    __shared__ int lastA;
    const int t = threadIdx.x;
    const int b = t & 63;
    const int hb = __builtin_amdgcn_readfirstlane(blockIdx.x * 16 + (t >> 6) * 4);
    const int k0 = blockIdx.y * 64;
    if (t < 64) idxl[t] = seq[t];
    __syncthreads();
    {   // stage x/h [64][64]: 4 threads per row, 16B chunks
        const int r = t >> 2;
        const int c = (t & 3) * 16;
        #pragma unroll
        for (int q = 0; q < 4; ++q) {
            const float4 xv = *(const float4*)&emb[(size_t)idxl[r] * NE + k0 + c + q*4];
            const float4 hv = *(const float4*)&lh[r * NH + k0 + c + q*4];
            xl[r][c+q*4+0]=xv.x; xl[r][c+q*4+1]=xv.y; xl[r][c+q*4+2]=xv.z; xl[r][c+q*4+3]=xv.w;
            hl[r][c+q*4+0]=hv.x; hl[r][c+q*4+1]=hv.y; hl[r][c+q*4+2]=hv.z; hl[r][c+q*4+3]=hv.w;
        }
    }
    __syncthreads();
    float air[4]={0,0,0,0}, aiz[4]={0,0,0,0}, ain[4]={0,0,0,0};
    float ahr[4]={0,0,0,0}, ahz[4]={0,0,0,0}, ahn[4]={0,0,0,0};
    #pragma unroll 2
    for (int e = 0; e < 64; e += 4) {
        const float x0=xl[b][e], x1=xl[b][e+1], x2=xl[b][e+2], x3=xl[b][e+3];
        const float h0v=hl[b][e], h1v=hl[b][e+1], h2v=hl[b][e+2], h3v=hl[b][e+3];
        #pragma unroll
        for (int hh = 0; hh < 4; ++hh) {
            const int h = hb + hh;
            const float4 wr = *(const float4*)&wih[(size_t)h*NE + k0 + e];
            const float4 wz = *(const float4*)&wih[(size_t)(512+h)*NE + k0 + e];
            const float4 wn = *(const float4*)&wih[(size_t)(1024+h)*NE + k0 + e];
            const float4 vr = *(const float4*)&whh[(size_t)h*NH + k0 + e];
            const float4 vz = *(const float4*)&whh[(size_t)(512+h)*NH + k0 + e];
            const float4 vn = *(const float4*)&whh[(size_t)(1024+h)*NH + k0 + e];
            air[hh] = fmaf(x0,wr.x, fmaf(x1,wr.y, fmaf(x2,wr.z, fmaf(x3,wr.w, air[hh]))));
            aiz[hh] = fmaf(x0,wz.x, fmaf(x1,wz.y, fmaf(x2,wz.z, fmaf(x3,wz.w, aiz[hh]))));
            ain[hh] = fmaf(x0,wn.x, fmaf(x1,wn.y, fmaf(x2,wn.z, fmaf(x3,wn.w, ain[hh]))));
            ahr[hh] = fmaf(h0v,vr.x, fmaf(h1v,vr.y, fmaf(h2v,vr.z, fmaf(h3v,vr.w, ahr[hh]))));
            ahz[hh] = fmaf(h0v,vz.x, fmaf(h1v,vz.y, fmaf(h2v,vz.z, fmaf(h3v,vz.w, ahz[hh]))));
            ahn[hh] = fmaf(h0v,vn.x, fmaf(h1v,vn.y, fmaf(h2v,vn.z, fmaf(h3v,vn.w, ahn[hh]))));
        }
    }
    float* gi = ws + GI_OFF + (size_t)blockIdx.y * H3 * NB;
    float* gh = ws + GH_OFF + (size_t)blockIdx.y * H3 * NB;
    #pragma unroll
    for (int hh = 0; hh < 4; ++hh) {
        const int h = hb + hh;
        gi[h*NB + b] = air[hh];  gi[(512+h)*NB + b] = aiz[hh];  gi[(1024+h)*NB + b] = ain[hh];
        gh[h*NB + b] = ahr[hh];  gh[(512+h)*NB + b] = ahz[hh];  gh[(1024+h)*NB + b] = ahn[hh];
    }
    __threadfence();
    if (t == 0) lastA = (atomicAdd(&cnt[blockIdx.x], 1u) == KSL - 1);
    __syncthreads();
    if (lastA) {
        __threadfence();
        #pragma unroll
        for (int hh = 0; hh < 4; ++hh) {
            const int h = hb + hh;
            float ir = bih[h], iz = bih[512+h], inn = bih[1024+h];
            float hr = bhh[h], hz = bhh[512+h], hnn = bhh[1024+h];
            #pragma unroll
            for (int s = 0; s < KSL; ++s) {
                const float* gis = ws + GI_OFF + (size_t)s * H3 * NB;
                const float* ghs = ws + GH_OFF + (size_t)s * H3 * NB;
                ir  += gis[h*NB+b];  iz  += gis[(512+h)*NB+b];  inn += gis[(1024+h)*NB+b];
                hr  += ghs[h*NB+b];  hz  += ghs[(512+h)*NB+b];  hnn += ghs[(1024+h)*NB+b];
            }
            const float r = 1.f / (1.f + __expf(-(ir + hr)));
            const float z = 1.f / (1.f + __expf(-(iz + hz)));
            const float nx = inn + r * hnn;
            const float e2 = __expf(-2.f * fabsf(nx));
            const float n = copysignf((1.f - e2) / (1.f + e2), nx);
            const float hnew = (1.f - z) * n + z * lh[b*NH + h];
            ws[HNEW_OFF + b*NH + h] = hnew;
            out[HID_OFF + (size_t)b*NH + h] = hnew;
        }
    }
}

// kB: flash attention + fused combine. grid 2048 = b(64) x chunk(32).
// Last chunk block per b (device atomic) does the softmax combine: ctx,
// attn output. enc loads nontemporal (stream; keep w_out L3-warm).
__global__ __launch_bounds__(256) void kB_attn(
    const float* __restrict__ enc, float* __restrict__ ws,
    float* __restrict__ out, unsigned* __restrict__ cnt)
{
    const int t = threadIdx.x;
    const int w = t >> 6;
    const int l = t & 63;
    const int b = blockIdx.x >> 5;
    const int chunk = blockIdx.x & 31;
    const float* hn = ws + HNEW_OFF + b * NH;
    const float4 hq0 = *(const float4*)&hn[l*4];
    const float4 hq1 = *(const float4*)&hn[256 + l*4];
    const int s0 = chunk * 64 + w * 16;
    const float* rowb = enc + ((size_t)s0 * NB + b) * NH;
    float m = -INFINITY, lsum = 0.f;
    float cx[8] = {0.f,0.f,0.f,0.f,0.f,0.f,0.f,0.f};
    float ekeep = 0.f;
    f32x4 a0 = __builtin_nontemporal_load((const f32x4*)&rowb[l*4]);
    f32x4 a1 = __builtin_nontemporal_load((const f32x4*)&rowb[256 + l*4]);
    for (int i = 0; i < 16; ++i) {
        const f32x4 r0 = a0, r1 = a1;
        if (i < 15) {
            const float* nr = rowb + (size_t)(i+1) * NB * NH;
            a0 = __builtin_nontemporal_load((const f32x4*)&nr[l*4]);
            a1 = __builtin_nontemporal_load((const f32x4*)&nr[256 + l*4]);
        }
        float d = r0.x*hq0.x;
        d = fmaf(r0.y,hq0.y,d); d = fmaf(r0.z,hq0.z,d); d = fmaf(r0.w,hq0.w,d);
        d = fmaf(r1.x,hq1.x,d); d = fmaf(r1.y,hq1.y,d); d = fmaf(r1.z,hq1.z,d); d = fmaf(r1.w,hq1.w,d);
        d += __shfl_xor(d, 32);
        d += __shfl_xor(d, 16);
        d += __shfl_xor(d, 8);
        d += __shfl_xor(d, 4);
        d += __shfl_xor(d, 2);
        d += __shfl_xor(d, 1);
        if (l == i) ekeep = d;
        const float mn = fmaxf(m, d);
        if (mn > m) {   // wave-uniform (d uniform after full reduce)
            const float sc = __expf(m - mn);
            lsum *= sc;
            #pragma unroll
            for (int k = 0; k < 8; ++k) cx[k] *= sc;
            m = mn;
        }
        const float p = __expf(d - m);
        lsum += p;
        cx[0]=fmaf(p,r0.x,cx[0]); cx[1]=fmaf(p,r0.y,cx[1]);
        cx[2]=fmaf(p,r0.z,cx[2]); cx[3]=fmaf(p,r0.w,cx[3]);
        cx[4]=fmaf(p,r1.x,cx[4]); cx[5]=fmaf(p,r1.y,cx[5]);
        cx[6]=fmaf(p,r1.z,cx[6]); cx[7]=fmaf(p,r1.w,cx[7]);
    }
    if (l < 16) ws[EN_OFF + (size_t)b * NS + s0 + l] = ekeep;
    __shared__ float ctxl[4][NH];
    __shared__ float ml[4], ll[4];
    __shared__ float pwl[NCH];
    __shared__ float Ml, invLl;
    __shared__ int lastB;
    #pragma unroll
    for (int k = 0; k < 4; ++k) {
        ctxl[w][l*4+k]       = cx[k];
        ctxl[w][256 + l*4+k] = cx[4+k];
    }
    if (l == 0) { ml[w] = m; ll[w] = lsum; }
    __syncthreads();
    const float M = fmaxf(fmaxf(ml[0], ml[1]), fmaxf(ml[2], ml[3]));
    const float w0 = __expf(ml[0]-M), w1 = __expf(ml[1]-M);
    const float w2 = __expf(ml[2]-M), w3 = __expf(ml[3]-M);
    for (int e = t; e < NH; e += 256) {
        const float c = ctxl[0][e]*w0 + ctxl[1][e]*w1 + ctxl[2][e]*w2 + ctxl[3][e]*w3;
        ws[PCTX_OFF + ((size_t)b*NCH + chunk)*NH + e] = c;
    }
    if (t == 0) {
        ws[PM_OFF + b*NCH + chunk] = M;
        ws[PL_OFF + b*NCH + chunk] = ll[0]*w0 + ll[1]*w1 + ll[2]*w2 + ll[3]*w3;
    }
    __threadfence();
    if (t == 0) lastB = (atomicAdd(&cnt[b], 1u) == NCH - 1);
    __syncthreads();
    if (!lastB) return;
    // ---- combine for this b (runs in exactly one block) ----
    __threadfence();
    if (t < NCH) pwl[t] = ws[PM_OFF + b*NCH + t];
    __syncthreads();
    if (t == 0) {
        float Mx = -INFINITY;
        #pragma unroll
        for (int c = 0; c < NCH; ++c) Mx = fmaxf(Mx, pwl[c]);
        Ml = Mx;
    }
    __syncthreads();
    if (t < NCH) pwl[t] = __expf(pwl[t] - Ml);
    __syncthreads();
    if (t == 0) {
        float L = 0.f;
        #pragma unroll
        for (int c = 0; c < NCH; ++c) L += ws[PL_OFF + b*NCH + c] * pwl[c];
        invLl = 1.f / L;
    }
    __syncthreads();
    const float Mx = Ml, invL = invLl;
    for (int e = t; e < NH; e += 256) {
        float acc = 0.f;
        #pragma unroll 8
        for (int c = 0; c < NCH; ++c)
            acc += ws[PCTX_OFF + ((size_t)b*NCH + c)*NH + e] * pwl[c];
        ws[CTX_OFF + b*NH + e] = acc * invL;
    }
    for (int s = t; s < NS; s += 256)
        out[ATTN_OFF + (size_t)b*NS + s] = __expf(ws[EN_OFF + (size_t)b*NS + s] - Mx) * invL;
}

// kC: concat GEMM [64,1024]@w_concat.T fused with bias+tanh+bf16 store.
// grid 64 blocks x 8 j, K=1024 staged in 16 LDS chunks.
__global__ __launch_bounds__(256) void kC_concat(
    const float* __restrict__ wcat, const float* __restrict__ bcat,
    float* __restrict__ ws)
{
    __shared__ float al[64][65];
    const int t = threadIdx.x;
    const int b = t & 63;
    const int j0 = __builtin_amdgcn_readfirstlane(blockIdx.x * 8 + (t >> 6) * 2);
    float acc0 = 0.f, acc1 = 0.f;
    for (int ch = 0; ch < 16; ++ch) {
        const float* A = ws + ((ch < 8) ? (HNEW_OFF + ch*64) : (CTX_OFF + (ch-8)*64));
        __syncthreads();
        {
            const int r = t >> 2;
            const int c = (t & 3) * 16;
            #pragma unroll
            for (int q = 0; q < 4; ++q) {
                const float4 v = *(const float4*)&A[r * NH + c + q*4];
                al[r][c+q*4+0]=v.x; al[r][c+q*4+1]=v.y; al[r][c+q*4+2]=v.z; al[r][c+q*4+3]=v.w;
            }
        }
        __syncthreads();
        #pragma unroll 4
        for (int e = 0; e < 64; e += 4) {
            const float x0=al[b][e], x1=al[b][e+1], x2=al[b][e+2], x3=al[b][e+3];
            const float4 q0 = *(const float4*)&wcat[(size_t)j0*1024 + ch*64 + e];
            const float4 q1 = *(const float4*)&wcat[(size_t)(j0+1)*1024 + ch*64 + e];
            acc0 = fmaf(x0,q0.x, fmaf(x1,q0.y, fmaf(x2,q0.z, fmaf(x3,q0.w, acc0))));
            acc1 = fmaf(x0,q1.x, fmaf(x1,q1.y, fmaf(x2,q1.z, fmaf(x3,q1.w, acc1))));
        }
    }
    unsigned short* ccb = (unsigned short*)(ws + CCB_OFF);
    {
        const float v = acc0 + bcat[j0];
        const float e2 = __expf(-2.f * fabsf(v));
        ccb[b*NH + j0] = f2bf(copysignf((1.f - e2) / (1.f + e2), v));
    }
    {
        const float v = acc1 + bcat[j0+1];
        const float e2 = __expf(-2.f * fabsf(v));
        ccb[b*NH + j0+1] = f2bf(copysignf((1.f - e2) / (1.f + e2), v));
    }
}

// k6: vocab projection via bf16 MFMA; w_out f32->bf16 via v_cvt_pk_bf16_f32.
__global__ __launch_bounds__(128) void k6_mfma(
    const float* __restrict__ wout, const float* __restrict__ bout,
    const unsigned short* __restrict__ ccb, float* __restrict__ out)
{
    const int t = threadIdx.x;
    const int w = t >> 6;
    const int l = t & 63;
    const int lm = l & 15;
    const int kg = l >> 4;
    const int j = blockIdx.x * 32 + w * 16 + lm;
    const int jc = j < NV ? j : NV - 1;
    const float* wrow = wout + (size_t)jc * NH + kg * 8;
    f32x4 acc0 = {0.f,0.f,0.f,0.f};
    f32x4 acc1 = {0.f,0.f,0.f,0.f};
    f32x4 acc2 = {0.f,0.f,0.f,0.f};
    f32x4 acc3 = {0.f,0.f,0.f,0.f};
    #pragma unroll 4
    for (int ks = 0; ks < 16; ++ks) {
        const float4 w0 = *(const float4*)(wrow + ks * 32);
        const float4 w1 = *(const float4*)(wrow + ks * 32 + 4);
        union { bf16x8 v; unsigned u[4]; } bb;
        asm("v_cvt_pk_bf16_f32 %0, %1, %2" : "=v"(bb.u[0]) : "v"(w0.x), "v"(w0.y));
        asm("v_cvt_pk_bf16_f32 %0, %1, %2" : "=v"(bb.u[1]) : "v"(w0.z), "v"(w0.w));
        asm("v_cvt_pk_bf16_f32 %0, %1, %2" : "=v"(bb.u[2]) : "v"(w1.x), "v"(w1.y));
        asm("v_cvt_pk_bf16_f32 %0, %1, %2" : "=v"(bb.u[3]) : "v"(w1.z), "v"(w1.w));
        const int ka = ks * 32 + kg * 8;
        const bf16x8 a0 = *(const bf16x8*)&ccb[(0*16 + lm) * NH + ka];
        const bf16x8 a1 = *(const bf16x8*)&ccb[(1*16 + lm) * NH + ka];
        const bf16x8 a2 = *(const bf16x8*)&ccb[(2*16 + lm) * NH + ka];
        const bf16x8 a3 = *(const bf16x8*)&ccb[(3*16 + lm) * NH + ka];
        acc0 = __builtin_amdgcn_mfma_f32_16x16x32_bf16(a0, bb.v, acc0, 0, 0, 0);
        acc1 = __builtin_amdgcn_mfma_f32_16x16x32_bf16(a1, bb.v, acc1, 0, 0, 0);
        acc2 = __builtin_amdgcn_mfma_f32_16x16x32_bf16(a2, bb.v, acc2, 0, 0, 0);
        acc3 = __builtin_amdgcn_mfma_f32_16x16x32_bf16(a3, bb.v, acc3, 0, 0, 0);
    }
    if (j < NV) {
        const float bj = bout[jc];
        #pragma unroll
        for (int r = 0; r < 4; ++r) {
            out[(size_t)(0*16 + kg*4 + r) * NV + j] = acc0[r] + bj;
            out[(size_t)(1*16 + kg*4 + r) * NV + j] = acc1[r] + bj;
            out[(size_t)(2*16 + kg*4 + r) * NV + j] = acc2[r] + bj;
            out[(size_t)(3*16 + kg*4 + r) * NV + j] = acc3[r] + bj;
        }
    }
}

extern "C" void kernel_launch(void* const* d_in, const int* in_sizes, int n_in,
                              void* d_out, int out_size, void* d_ws, size_t ws_size,
                              hipStream_t stream) {
    (void)in_sizes; (void)n_in; (void)out_size; (void)ws_size;
    const int*   seq  = (const int*)  d_in[0];
    const float* lh   = (const float*)d_in[1];
    const float* enc  = (const float*)d_in[2];
    const float* emb  = (const float*)d_in[3];
    const float* wih  = (const float*)d_in[4];
    const float* whh  = (const float*)d_in[5];
    const float* bih  = (const float*)d_in[6];
    const float* bhh  = (const float*)d_in[7];
    const float* wcat = (const float*)d_in[8];
    const float* bcat = (const float*)d_in[9];
    const float* wout = (const float*)d_in[10];
    const float* bout = (const float*)d_in[11];
    float* out = (float*)d_out;
    float* ws  = (float*)d_ws;
    unsigned* cnt = (unsigned*)(ws + CNT_OFF);

    hipMemsetAsync(cnt, 0, 512, stream);   // zero kA (32) + kB (64) counters
    kA_gru   <<<dim3(32, KSL), 256, 0, stream>>>(seq, lh, emb, wih, whh, bih, bhh, ws, out, cnt);
    kB_attn  <<<2048, 256, 0, stream>>>(enc, ws, out, cnt + 32);
    kC_concat<<<64, 256, 0, stream>>>(wcat, bcat, ws);
    k6_mfma  <<<1571, 128, 0, stream>>>(wout, bout,
                  (const unsigned short*)(ws + CCB_OFF), out);
}

// Round 6
// 145.309 us; speedup vs baseline: 4.0742x; 4.0742x over previous
//
#include <hip/hip_runtime.h>
#include <math.h>

#define NB 64
#define NS 2048
#define NH 512
#define NE 512
#define NV 50257
#define H3 1536
#define KSL 8          // k1 split-K slices
#define NCH 32         // k3 s-chunks per b

typedef __attribute__((ext_vector_type(8))) short bf16x8;
typedef __attribute__((ext_vector_type(4))) float f32x4;

// ---- workspace layout (float offsets) ----
#define GI_OFF    0                            // [8][1536][64] gi split-K partials
#define GH_OFF    (GI_OFF + KSL*H3*NB)         // [8][1536][64]
#define HNEW_OFF  (GH_OFF + KSL*H3*NB)         // [64][512]
#define EN_OFF    (HNEW_OFF + NB*NH)           // [64][2048] raw energies
#define PCTX_OFF  (EN_OFF + NB*NS)             // [64][32][512] partial ctx
#define PM_OFF    (PCTX_OFF + NB*NCH*NH)       // [64][32] partial max
#define PL_OFF    (PM_OFF + NB*NCH)            // [64][32] partial sum
#define CTX_OFF   (PL_OFF + NB*NCH)            // [64][512]
#define CCB_OFF   (CTX_OFF + NB*NH)            // [64][512] concat_output bf16 (ushort)

// ---- d_out layout (float offsets) ----
#define HID_OFF  ((size_t)NB*NV)
#define ATTN_OFF (HID_OFF + (size_t)NB*NH)

__device__ __forceinline__ unsigned short f2bf(float f) {
    unsigned u = __builtin_bit_cast(unsigned, f);
    u += 0x7FFFu + ((u >> 16) & 1u);   // RNE
    return (unsigned short)(u >> 16);
}

// K1: split-K(8) GRU input GEMMs. grid (96 j-tiles, 8 k-slices). lane=b, 4 j/thread.
__global__ __launch_bounds__(256) void k1_gru_gemm(
    const int* __restrict__ seq, const float* __restrict__ lh,
    const float* __restrict__ emb, const float* __restrict__ wih,
    const float* __restrict__ whh, float* __restrict__ ws)
{
    __shared__ float xl[64][65];
    __shared__ float hl[64][65];
    __shared__ int idxl[64];
    const int t = threadIdx.x;
    const int b = t & 63;
    const int j0 = __builtin_amdgcn_readfirstlane(blockIdx.x * 16 + (t >> 6) * 4);
    const int k0 = blockIdx.y * 64;
    if (t < 64) idxl[t] = seq[t];
    __syncthreads();
    {   // stage x/h [64][64]: 4 threads per row, 16B chunks
        const int r = t >> 2;
        const int c = (t & 3) * 16;
        #pragma unroll
        for (int q = 0; q < 4; ++q) {
            const float4 xv = *(const float4*)&emb[(size_t)idxl[r] * NE + k0 + c + q*4];
            const float4 hv = *(const float4*)&lh[r * NH + k0 + c + q*4];
            xl[r][c+q*4+0]=xv.x; xl[r][c+q*4+1]=xv.y; xl[r][c+q*4+2]=xv.z; xl[r][c+q*4+3]=xv.w;
            hl[r][c+q*4+0]=hv.x; hl[r][c+q*4+1]=hv.y; hl[r][c+q*4+2]=hv.z; hl[r][c+q*4+3]=hv.w;
        }
    }
    __syncthreads();
    float ai[4] = {0.f,0.f,0.f,0.f};
    float ah[4] = {0.f,0.f,0.f,0.f};
    #pragma unroll 4
    for (int e = 0; e < 64; e += 4) {
        const float x0=xl[b][e], x1=xl[b][e+1], x2=xl[b][e+2], x3=xl[b][e+3];
        const float h0=hl[b][e], h1=hl[b][e+1], h2=hl[b][e+2], h3=hl[b][e+3];
        #pragma unroll
        for (int jj = 0; jj < 4; ++jj) {
            const float4 wi = *(const float4*)&wih[(size_t)(j0+jj)*NE + k0 + e];
            const float4 wh = *(const float4*)&whh[(size_t)(j0+jj)*NH + k0 + e];
            ai[jj] = fmaf(x0,wi.x, fmaf(x1,wi.y, fmaf(x2,wi.z, fmaf(x3,wi.w, ai[jj]))));
            ah[jj] = fmaf(h0,wh.x, fmaf(h1,wh.y, fmaf(h2,wh.z, fmaf(h3,wh.w, ah[jj]))));
        }
    }
    float* gi = ws + GI_OFF + (size_t)blockIdx.y * H3 * NB;
    float* gh = ws + GH_OFF + (size_t)blockIdx.y * H3 * NB;
    #pragma unroll
    for (int jj = 0; jj < 4; ++jj) {
        gi[(j0+jj)*NB + b] = ai[jj];
        gh[(j0+jj)*NB + b] = ah[jj];
    }
}

// K2: combine 8 split-K partials + biases, GRU gate math -> h_new
__global__ __launch_bounds__(256) void k2_gates(
    const float* __restrict__ lh, const float* __restrict__ bih,
    const float* __restrict__ bhh, float* __restrict__ ws, float* __restrict__ out)
{
    const int gid = blockIdx.x * 256 + threadIdx.x;
    const int b = gid & 63;
    const int h = gid >> 6;
    const float* gi = ws + GI_OFF;
    const float* gh = ws + GH_OFF;
    const int P = H3 * NB;
    float ir = bih[h], iz = bih[512+h], inn = bih[1024+h];
    float hr = bhh[h], hz = bhh[512+h], hnn = bhh[1024+h];
    #pragma unroll
    for (int s = 0; s < KSL; ++s) {
        ir  += gi[s*P + h*NB + b];
        iz  += gi[s*P + (512+h)*NB + b];
        inn += gi[s*P + (1024+h)*NB + b];
        hr  += gh[s*P + h*NB + b];
        hz  += gh[s*P + (512+h)*NB + b];
        hnn += gh[s*P + (1024+h)*NB + b];
    }
    const float r = 1.f / (1.f + __expf(-(ir + hr)));
    const float z = 1.f / (1.f + __expf(-(iz + hz)));
    const float nx = inn + r * hnn;
    const float e2 = __expf(-2.f * fabsf(nx));
    const float n = copysignf((1.f - e2) / (1.f + e2), nx);
    const float hnew = (1.f - z) * n + z * lh[b*NH + h];
    ws[HNEW_OFF + b*NH + h] = hnew;
    out[HID_OFF + (size_t)b*NH + h] = hnew;
}

// K3: flash-style attention pass. grid 2048 = b(64) x chunk(32); wave owns 16 s-rows.
// enc loads nontemporal (stream once; keep w_out L3-resident across replays).
// NO cross-block fences — kernel boundary is the sync (R5 lesson: device-scope
// __threadfence from 2048 blocks = serialized L2 flushes = 10x regression).
__global__ __launch_bounds__(256) void k3_attn(
    const float* __restrict__ enc, float* __restrict__ ws)
{
    const int t = threadIdx.x;
    const int w = t >> 6;
    const int l = t & 63;
    const int b = blockIdx.x >> 5;
    const int chunk = blockIdx.x & 31;
    const float* hn = ws + HNEW_OFF + b * NH;
    const float4 hq0 = *(const float4*)&hn[l*4];
    const float4 hq1 = *(const float4*)&hn[256 + l*4];
    const int s0 = chunk * 64 + w * 16;
    const float* rowb = enc + ((size_t)s0 * NB + b) * NH;
    float m = -INFINITY, lsum = 0.f;
    float cx[8] = {0.f,0.f,0.f,0.f,0.f,0.f,0.f,0.f};
    float ekeep = 0.f;
    f32x4 a0 = __builtin_nontemporal_load((const f32x4*)&rowb[l*4]);
    f32x4 a1 = __builtin_nontemporal_load((const f32x4*)&rowb[256 + l*4]);
    for (int i = 0; i < 16; ++i) {
        const f32x4 r0 = a0, r1 = a1;
        if (i < 15) {
            const float* nr = rowb + (size_t)(i+1) * NB * NH;
            a0 = __builtin_nontemporal_load((const f32x4*)&nr[l*4]);
            a1 = __builtin_nontemporal_load((const f32x4*)&nr[256 + l*4]);
        }
        float d = r0.x*hq0.x;
        d = fmaf(r0.y,hq0.y,d); d = fmaf(r0.z,hq0.z,d); d = fmaf(r0.w,hq0.w,d);
        d = fmaf(r1.x,hq1.x,d); d = fmaf(r1.y,hq1.y,d); d = fmaf(r1.z,hq1.z,d); d = fmaf(r1.w,hq1.w,d);
        d += __shfl_xor(d, 32);
        d += __shfl_xor(d, 16);
        d += __shfl_xor(d, 8);
        d += __shfl_xor(d, 4);
        d += __shfl_xor(d, 2);
        d += __shfl_xor(d, 1);
        if (l == i) ekeep = d;
        const float mn = fmaxf(m, d);
        if (mn > m) {   // wave-uniform (d uniform after full reduce)
            const float sc = __expf(m - mn);
            lsum *= sc;
            #pragma unroll
            for (int k = 0; k < 8; ++k) cx[k] *= sc;
            m = mn;
        }
        const float p = __expf(d - m);
        lsum += p;
        cx[0]=fmaf(p,r0.x,cx[0]); cx[1]=fmaf(p,r0.y,cx[1]);
        cx[2]=fmaf(p,r0.z,cx[2]); cx[3]=fmaf(p,r0.w,cx[3]);
        cx[4]=fmaf(p,r1.x,cx[4]); cx[5]=fmaf(p,r1.y,cx[5]);
        cx[6]=fmaf(p,r1.z,cx[6]); cx[7]=fmaf(p,r1.w,cx[7]);
    }
    if (l < 16) ws[EN_OFF + (size_t)b * NS + s0 + l] = ekeep;
    __shared__ float ctxl[4][NH];
    __shared__ float ml[4], ll[4];
    #pragma unroll
    for (int k = 0; k < 4; ++k) {
        ctxl[w][l*4+k]       = cx[k];
        ctxl[w][256 + l*4+k] = cx[4+k];
    }
    if (l == 0) { ml[w] = m; ll[w] = lsum; }
    __syncthreads();
    const float M = fmaxf(fmaxf(ml[0], ml[1]), fmaxf(ml[2], ml[3]));
    const float w0 = __expf(ml[0]-M), w1 = __expf(ml[1]-M);
    const float w2 = __expf(ml[2]-M), w3 = __expf(ml[3]-M);
    for (int e = t; e < NH; e += 256) {
        const float c = ctxl[0][e]*w0 + ctxl[1][e]*w1 + ctxl[2][e]*w2 + ctxl[3][e]*w3;
        ws[PCTX_OFF + ((size_t)b*NCH + chunk)*NH + e] = c;
    }
    if (t == 0) {
        ws[PM_OFF + b*NCH + chunk] = M;
        ws[PL_OFF + b*NCH + chunk] = ll[0]*w0 + ll[1]*w1 + ll[2]*w2 + ll[3]*w3;
    }
}

// K4: combine the 32 partials per b -> ctx (normalized) + attn output.
// grid (64 b, 4 slices) = 256 blocks (1/CU) for latency hiding.
__global__ __launch_bounds__(256) void k4_combine(
    float* __restrict__ ws, float* __restrict__ out)
{
    const int b = blockIdx.x;
    const int sl = blockIdx.y;
    const int t = threadIdx.x;
    __shared__ float pml[NCH], pll[NCH], pwl[NCH];
    if (t < NCH) { pml[t] = ws[PM_OFF + b*NCH + t]; pll[t] = ws[PL_OFF + b*NCH + t]; }
    __syncthreads();
    float M = -INFINITY;
    #pragma unroll
    for (int c = 0; c < NCH; ++c) M = fmaxf(M, pml[c]);
    if (t < NCH) pwl[t] = __expf(pml[t] - M);
    __syncthreads();
    float L = 0.f;
    #pragma unroll
    for (int c = 0; c < NCH; ++c) L += pll[c] * pwl[c];
    const float invL = 1.f / L;
    // ctx slice: 128 e's
    const int e = sl * 128 + (t & 127);
    if (t < 128) {
        float acc = 0.f;
        #pragma unroll 8
        for (int c = 0; c < NCH; ++c)
            acc += ws[PCTX_OFF + ((size_t)b*NCH + c)*NH + e] * pwl[c];
        ws[CTX_OFF + b*NH + e] = acc * invL;
    }
    // attn slice: 512 s's
    for (int s = sl * 512 + t; s < sl * 512 + 512; s += 256)
        out[ATTN_OFF + (size_t)b*NS + s] = __expf(ws[EN_OFF + (size_t)b*NS + s] - M) * invL;
}

// kC: concat GEMM [64,1024]@w_concat.T fused with bias+tanh+bf16 store.
// grid 64 blocks x 8 j, K=1024 staged in 16 LDS chunks. Intra-block only.
__global__ __launch_bounds__(256) void kC_concat(
    const float* __restrict__ wcat, const float* __restrict__ bcat,
    float* __restrict__ ws)
{
    __shared__ float al[64][65];
    const int t = threadIdx.x;
    const int b = t & 63;
    const int j0 = __builtin_amdgcn_readfirstlane(blockIdx.x * 8 + (t >> 6) * 2);
    float acc0 = 0.f, acc1 = 0.f;
    for (int ch = 0; ch < 16; ++ch) {
        const float* A = ws + ((ch < 8) ? (HNEW_OFF + ch*64) : (CTX_OFF + (ch-8)*64));
        __syncthreads();
        {
            const int r = t >> 2;
            const int c = (t & 3) * 16;
            #pragma unroll
            for (int q = 0; q < 4; ++q) {
                const float4 v = *(const float4*)&A[r * NH + c + q*4];
                al[r][c+q*4+0]=v.x; al[r][c+q*4+1]=v.y; al[r][c+q*4+2]=v.z; al[r][c+q*4+3]=v.w;
            }
        }
        __syncthreads();
        #pragma unroll 4
        for (int e = 0; e < 64; e += 4) {
            const float x0=al[b][e], x1=al[b][e+1], x2=al[b][e+2], x3=al[b][e+3];
            const float4 q0 = *(const float4*)&wcat[(size_t)j0*1024 + ch*64 + e];
            const float4 q1 = *(const float4*)&wcat[(size_t)(j0+1)*1024 + ch*64 + e];
            acc0 = fmaf(x0,q0.x, fmaf(x1,q0.y, fmaf(x2,q0.z, fmaf(x3,q0.w, acc0))));
            acc1 = fmaf(x0,q1.x, fmaf(x1,q1.y, fmaf(x2,q1.z, fmaf(x3,q1.w, acc1))));
        }
    }
    unsigned short* ccb = (unsigned short*)(ws + CCB_OFF);
    {
        const float v = acc0 + bcat[j0];
        const float e2 = __expf(-2.f * fabsf(v));
        ccb[b*NH + j0] = f2bf(copysignf((1.f - e2) / (1.f + e2), v));
    }
    {
        const float v = acc1 + bcat[j0+1];
        const float e2 = __expf(-2.f * fabsf(v));
        ccb[b*NH + j0+1] = f2bf(copysignf((1.f - e2) / (1.f + e2), v));
    }
}

// k6: vocab projection via bf16 MFMA; w_out f32->bf16 via v_cvt_pk_bf16_f32.
__global__ __launch_bounds__(128) void k6_mfma(
    const float* __restrict__ wout, const float* __restrict__ bout,
    const unsigned short* __restrict__ ccb, float* __restrict__ out)
{
    const int t = threadIdx.x;
    const int w = t >> 6;
    const int l = t & 63;
    const int lm = l & 15;
    const int kg = l >> 4;
    const int j = blockIdx.x * 32 + w * 16 + lm;
    const int jc = j < NV ? j : NV - 1;
    const float* wrow = wout + (size_t)jc * NH + kg * 8;
    f32x4 acc0 = {0.f,0.f,0.f,0.f};
    f32x4 acc1 = {0.f,0.f,0.f,0.f};
    f32x4 acc2 = {0.f,0.f,0.f,0.f};
    f32x4 acc3 = {0.f,0.f,0.f,0.f};
    #pragma unroll 4
    for (int ks = 0; ks < 16; ++ks) {
        const float4 w0 = *(const float4*)(wrow + ks * 32);
        const float4 w1 = *(const float4*)(wrow + ks * 32 + 4);
        union { bf16x8 v; unsigned u[4]; } bb;
        asm("v_cvt_pk_bf16_f32 %0, %1, %2" : "=v"(bb.u[0]) : "v"(w0.x), "v"(w0.y));
        asm("v_cvt_pk_bf16_f32 %0, %1, %2" : "=v"(bb.u[1]) : "v"(w0.z), "v"(w0.w));
        asm("v_cvt_pk_bf16_f32 %0, %1, %2" : "=v"(bb.u[2]) : "v"(w1.x), "v"(w1.y));
        asm("v_cvt_pk_bf16_f32 %0, %1, %2" : "=v"(bb.u[3]) : "v"(w1.z), "v"(w1.w));
        const int ka = ks * 32 + kg * 8;
        const bf16x8 a0 = *(const bf16x8*)&ccb[(0*16 + lm) * NH + ka];
        const bf16x8 a1 = *(const bf16x8*)&ccb[(1*16 + lm) * NH + ka];
        const bf16x8 a2 = *(const bf16x8*)&ccb[(2*16 + lm) * NH + ka];
        const bf16x8 a3 = *(const bf16x8*)&ccb[(3*16 + lm) * NH + ka];
        acc0 = __builtin_amdgcn_mfma_f32_16x16x32_bf16(a0, bb.v, acc0, 0, 0, 0);
        acc1 = __builtin_amdgcn_mfma_f32_16x16x32_bf16(a1, bb.v, acc1, 0, 0, 0);
        acc2 = __builtin_amdgcn_mfma_f32_16x16x32_bf16(a2, bb.v, acc2, 0, 0, 0);
        acc3 = __builtin_amdgcn_mfma_f32_16x16x32_bf16(a3, bb.v, acc3, 0, 0, 0);
    }
    if (j < NV) {
        const float bj = bout[jc];
        #pragma unroll
        for (int r = 0; r < 4; ++r) {
            out[(size_t)(0*16 + kg*4 + r) * NV + j] = acc0[r] + bj;
            out[(size_t)(1*16 + kg*4 + r) * NV + j] = acc1[r] + bj;
            out[(size_t)(2*16 + kg*4 + r) * NV + j] = acc2[r] + bj;
            out[(size_t)(3*16 + kg*4 + r) * NV + j] = acc3[r] + bj;
        }
    }
}

extern "C" void kernel_launch(void* const* d_in, const int* in_sizes, int n_in,
                              void* d_out, int out_size, void* d_ws, size_t ws_size,
                              hipStream_t stream) {
    (void)in_sizes; (void)n_in; (void)out_size; (void)ws_size;
    const int*   seq  = (const int*)  d_in[0];
    const float* lh   = (const float*)d_in[1];
    const float* enc  = (const float*)d_in[2];
    const float* emb  = (const float*)d_in[3];
    const float* wih  = (const float*)d_in[4];
    const float* whh  = (const float*)d_in[5];
    const float* bih  = (const float*)d_in[6];
    const float* bhh  = (const float*)d_in[7];
    const float* wcat = (const float*)d_in[8];
    const float* bcat = (const float*)d_in[9];
    const float* wout = (const float*)d_in[10];
    const float* bout = (const float*)d_in[11];
    float* out = (float*)d_out;
    float* ws  = (float*)d_ws;

    k1_gru_gemm <<<dim3(96, KSL), 256, 0, stream>>>(seq, lh, emb, wih, whh, ws);
    k2_gates    <<<128, 256, 0, stream>>>(lh, bih, bhh, ws, out);
    k3_attn     <<<2048, 256, 0, stream>>>(enc, ws);
    k4_combine  <<<dim3(64, 4), 256, 0, stream>>>(ws, out);
    kC_concat   <<<64, 256, 0, stream>>>(wcat, bcat, ws);
    k6_mfma     <<<1571, 128, 0, stream>>>(wout, bout,
                     (const unsigned short*)(ws + CCB_OFF), out);
}

// Round 7
// 131.130 us; speedup vs baseline: 4.5148x; 1.1081x over previous
//
#include <hip/hip_runtime.h>
#include <math.h>

#define NB 64
#define NS 2048
#define NH 512
#define NE 512
#define NV 50257
#define H3 1536
#define KSL 8          // k1 split-K slices
#define NCH 32         // k3 s-chunks per b

typedef __attribute__((ext_vector_type(8))) short bf16x8;
typedef __attribute__((ext_vector_type(4))) float f32x4;

// ---- workspace layout (float offsets) ----
#define GI_OFF    0                            // [8][1536][64] gi split-K partials
#define GH_OFF    (GI_OFF + KSL*H3*NB)         // [8][1536][64]
#define HNEW_OFF  (GH_OFF + KSL*H3*NB)         // [64][512]
#define EN_OFF    (HNEW_OFF + NB*NH)           // [64][2048] raw energies
#define PCTX_OFF  (EN_OFF + NB*NS)             // [64][32][512] partial ctx
#define PM_OFF    (PCTX_OFF + NB*NCH*NH)       // [64][32] partial max
#define PL_OFF    (PM_OFF + NB*NCH)            // [64][32] partial sum
#define CPART_OFF (PL_OFF + NB*NCH)            // [4][512][64] concat partials
#define CTX_OFF   (CPART_OFF + 4*NH*NB)        // [64][512]
#define CCB_OFF   (CTX_OFF + NB*NH)            // [64][512] concat_output bf16 (ushort)

// ---- d_out layout (float offsets) ----
#define HID_OFF  ((size_t)NB*NV)
#define ATTN_OFF (HID_OFF + (size_t)NB*NH)

__device__ __forceinline__ unsigned short f2bf(float f) {
    unsigned u = __builtin_bit_cast(unsigned, f);
    u += 0x7FFFu + ((u >> 16) & 1u);   // RNE
    return (unsigned short)(u >> 16);
}

// K1: split-K(8) GRU input GEMMs. grid (96 j-tiles, 8 k-slices). lane=b, 4 j/thread.
__global__ __launch_bounds__(256) void k1_gru_gemm(
    const int* __restrict__ seq, const float* __restrict__ lh,
    const float* __restrict__ emb, const float* __restrict__ wih,
    const float* __restrict__ whh, float* __restrict__ ws)
{
    __shared__ float xl[64][65];
    __shared__ float hl[64][65];
    __shared__ int idxl[64];
    const int t = threadIdx.x;
    const int b = t & 63;
    const int j0 = __builtin_amdgcn_readfirstlane(blockIdx.x * 16 + (t >> 6) * 4);
    const int k0 = blockIdx.y * 64;
    if (t < 64) idxl[t] = seq[t];
    __syncthreads();
    {   // stage x/h [64][64]: 4 threads per row, 16B chunks
        const int r = t >> 2;
        const int c = (t & 3) * 16;
        #pragma unroll
        for (int q = 0; q < 4; ++q) {
            const float4 xv = *(const float4*)&emb[(size_t)idxl[r] * NE + k0 + c + q*4];
            const float4 hv = *(const float4*)&lh[r * NH + k0 + c + q*4];
            xl[r][c+q*4+0]=xv.x; xl[r][c+q*4+1]=xv.y; xl[r][c+q*4+2]=xv.z; xl[r][c+q*4+3]=xv.w;
            hl[r][c+q*4+0]=hv.x; hl[r][c+q*4+1]=hv.y; hl[r][c+q*4+2]=hv.z; hl[r][c+q*4+3]=hv.w;
        }
    }
    __syncthreads();
    float ai[4] = {0.f,0.f,0.f,0.f};
    float ah[4] = {0.f,0.f,0.f,0.f};
    #pragma unroll 4
    for (int e = 0; e < 64; e += 4) {
        const float x0=xl[b][e], x1=xl[b][e+1], x2=xl[b][e+2], x3=xl[b][e+3];
        const float h0=hl[b][e], h1=hl[b][e+1], h2=hl[b][e+2], h3=hl[b][e+3];
        #pragma unroll
        for (int jj = 0; jj < 4; ++jj) {
            const float4 wi = *(const float4*)&wih[(size_t)(j0+jj)*NE + k0 + e];
            const float4 wh = *(const float4*)&whh[(size_t)(j0+jj)*NH + k0 + e];
            ai[jj] = fmaf(x0,wi.x, fmaf(x1,wi.y, fmaf(x2,wi.z, fmaf(x3,wi.w, ai[jj]))));
            ah[jj] = fmaf(h0,wh.x, fmaf(h1,wh.y, fmaf(h2,wh.z, fmaf(h3,wh.w, ah[jj]))));
        }
    }
    float* gi = ws + GI_OFF + (size_t)blockIdx.y * H3 * NB;
    float* gh = ws + GH_OFF + (size_t)blockIdx.y * H3 * NB;
    #pragma unroll
    for (int jj = 0; jj < 4; ++jj) {
        gi[(j0+jj)*NB + b] = ai[jj];
        gh[(j0+jj)*NB + b] = ah[jj];
    }
}

// K2: combine 8 split-K partials + biases, GRU gate math -> h_new
__global__ __launch_bounds__(256) void k2_gates(
    const float* __restrict__ lh, const float* __restrict__ bih,
    const float* __restrict__ bhh, float* __restrict__ ws, float* __restrict__ out)
{
    const int gid = blockIdx.x * 256 + threadIdx.x;
    const int b = gid & 63;
    const int h = gid >> 6;
    const float* gi = ws + GI_OFF;
    const float* gh = ws + GH_OFF;
    const int P = H3 * NB;
    float ir = bih[h], iz = bih[512+h], inn = bih[1024+h];
    float hr = bhh[h], hz = bhh[512+h], hnn = bhh[1024+h];
    #pragma unroll
    for (int s = 0; s < KSL; ++s) {
        ir  += gi[s*P + h*NB + b];
        iz  += gi[s*P + (512+h)*NB + b];
        inn += gi[s*P + (1024+h)*NB + b];
        hr  += gh[s*P + h*NB + b];
        hz  += gh[s*P + (512+h)*NB + b];
        hnn += gh[s*P + (1024+h)*NB + b];
    }
    const float r = 1.f / (1.f + __expf(-(ir + hr)));
    const float z = 1.f / (1.f + __expf(-(iz + hz)));
    const float nx = inn + r * hnn;
    const float e2 = __expf(-2.f * fabsf(nx));
    const float n = copysignf((1.f - e2) / (1.f + e2), nx);
    const float hnew = (1.f - z) * n + z * lh[b*NH + h];
    ws[HNEW_OFF + b*NH + h] = hnew;
    out[HID_OFF + (size_t)b*NH + h] = hnew;
}

// K3: flash-style attention pass. grid 2048 = b(64) x chunk(32); wave owns 16 s-rows.
// enc loads nontemporal. Kernel boundary is the sync (R5 lesson: device-scope
// __threadfence from 2048 blocks = serialized L2 flushes = 10x regression).
__global__ __launch_bounds__(256) void k3_attn(
    const float* __restrict__ enc, float* __restrict__ ws)
{
    const int t = threadIdx.x;
    const int w = t >> 6;
    const int l = t & 63;
    const int b = blockIdx.x >> 5;
    const int chunk = blockIdx.x & 31;
    const float* hn = ws + HNEW_OFF + b * NH;
    const float4 hq0 = *(const float4*)&hn[l*4];
    const float4 hq1 = *(const float4*)&hn[256 + l*4];
    const int s0 = chunk * 64 + w * 16;
    const float* rowb = enc + ((size_t)s0 * NB + b) * NH;
    float m = -INFINITY, lsum = 0.f;
    float cx[8] = {0.f,0.f,0.f,0.f,0.f,0.f,0.f,0.f};
    float ekeep = 0.f;
    f32x4 a0 = __builtin_nontemporal_load((const f32x4*)&rowb[l*4]);
    f32x4 a1 = __builtin_nontemporal_load((const f32x4*)&rowb[256 + l*4]);
    for (int i = 0; i < 16; ++i) {
        const f32x4 r0 = a0, r1 = a1;
        if (i < 15) {
            const float* nr = rowb + (size_t)(i+1) * NB * NH;
            a0 = __builtin_nontemporal_load((const f32x4*)&nr[l*4]);
            a1 = __builtin_nontemporal_load((const f32x4*)&nr[256 + l*4]);
        }
        float d = r0.x*hq0.x;
        d = fmaf(r0.y,hq0.y,d); d = fmaf(r0.z,hq0.z,d); d = fmaf(r0.w,hq0.w,d);
        d = fmaf(r1.x,hq1.x,d); d = fmaf(r1.y,hq1.y,d); d = fmaf(r1.z,hq1.z,d); d = fmaf(r1.w,hq1.w,d);
        d += __shfl_xor(d, 32);
        d += __shfl_xor(d, 16);
        d += __shfl_xor(d, 8);
        d += __shfl_xor(d, 4);
        d += __shfl_xor(d, 2);
        d += __shfl_xor(d, 1);
        if (l == i) ekeep = d;
        const float mn = fmaxf(m, d);
        if (mn > m) {   // wave-uniform (d uniform after full reduce)
            const float sc = __expf(m - mn);
            lsum *= sc;
            #pragma unroll
            for (int k = 0; k < 8; ++k) cx[k] *= sc;
            m = mn;
        }
        const float p = __expf(d - m);
        lsum += p;
        cx[0]=fmaf(p,r0.x,cx[0]); cx[1]=fmaf(p,r0.y,cx[1]);
        cx[2]=fmaf(p,r0.z,cx[2]); cx[3]=fmaf(p,r0.w,cx[3]);
        cx[4]=fmaf(p,r1.x,cx[4]); cx[5]=fmaf(p,r1.y,cx[5]);
        cx[6]=fmaf(p,r1.z,cx[6]); cx[7]=fmaf(p,r1.w,cx[7]);
    }
    if (l < 16) ws[EN_OFF + (size_t)b * NS + s0 + l] = ekeep;
    __shared__ float ctxl[4][NH];
    __shared__ float ml[4], ll[4];
    #pragma unroll
    for (int k = 0; k < 4; ++k) {
        ctxl[w][l*4+k]       = cx[k];
        ctxl[w][256 + l*4+k] = cx[4+k];
    }
    if (l == 0) { ml[w] = m; ll[w] = lsum; }
    __syncthreads();
    const float M = fmaxf(fmaxf(ml[0], ml[1]), fmaxf(ml[2], ml[3]));
    const float w0 = __expf(ml[0]-M), w1 = __expf(ml[1]-M);
    const float w2 = __expf(ml[2]-M), w3 = __expf(ml[3]-M);
    for (int e = t; e < NH; e += 256) {
        const float c = ctxl[0][e]*w0 + ctxl[1][e]*w1 + ctxl[2][e]*w2 + ctxl[3][e]*w3;
        ws[PCTX_OFF + ((size_t)b*NCH + chunk)*NH + e] = c;
    }
    if (t == 0) {
        ws[PM_OFF + b*NCH + chunk] = M;
        ws[PL_OFF + b*NCH + chunk] = ll[0]*w0 + ll[1]*w1 + ll[2]*w2 + ll[3]*w3;
    }
}

// K4: combine the 32 partials per b -> ctx (normalized) + attn output.
// grid (64 b, 4 slices) = 256 blocks (1/CU) for latency hiding.
__global__ __launch_bounds__(256) void k4_combine(
    float* __restrict__ ws, float* __restrict__ out)
{
    const int b = blockIdx.x;
    const int sl = blockIdx.y;
    const int t = threadIdx.x;
    __shared__ float pml[NCH], pll[NCH], pwl[NCH];
    if (t < NCH) { pml[t] = ws[PM_OFF + b*NCH + t]; pll[t] = ws[PL_OFF + b*NCH + t]; }
    __syncthreads();
    float M = -INFINITY;
    #pragma unroll
    for (int c = 0; c < NCH; ++c) M = fmaxf(M, pml[c]);
    if (t < NCH) pwl[t] = __expf(pml[t] - M);
    __syncthreads();
    float L = 0.f;
    #pragma unroll
    for (int c = 0; c < NCH; ++c) L += pll[c] * pwl[c];
    const float invL = 1.f / L;
    const int e = sl * 128 + (t & 127);
    if (t < 128) {
        float acc = 0.f;
        #pragma unroll 8
        for (int c = 0; c < NCH; ++c)
            acc += ws[PCTX_OFF + ((size_t)b*NCH + c)*NH + e] * pwl[c];
        ws[CTX_OFF + b*NH + e] = acc * invL;
    }
    for (int s = sl * 512 + t; s < sl * 512 + 512; s += 256)
        out[ATTN_OFF + (size_t)b*NS + s] = __expf(ws[EN_OFF + (size_t)b*NS + s] - M) * invL;
}

// K5: concat GEMM partials: [64,1024] @ w_concat.T, split-K over 4 chunks of 256
__global__ __launch_bounds__(256) void k5_concat_gemm(
    const float* __restrict__ wcat, float* __restrict__ ws)
{
    __shared__ float al[64][65];
    const int t = threadIdx.x;
    const int b = t & 63;
    const int j0 = __builtin_amdgcn_readfirstlane(blockIdx.x * 16 + (t >> 6) * 4);
    const int kc = blockIdx.y;
    const float* A = ws + ((kc < 2) ? HNEW_OFF : CTX_OFF);
    const int kb = (kc & 1) * 256;
    float acc[4] = {0.f,0.f,0.f,0.f};
    const int c4 = (t & 15) * 4;
    const int r0 = t >> 4;
    for (int ch = 0; ch < 4; ++ch) {
        const int k0 = kb + ch * 64;
        __syncthreads();
        #pragma unroll
        for (int i = 0; i < 4; ++i) {
            const int r = r0 + i * 16;
            const float4 v = *(const float4*)&A[r * NH + k0 + c4];
            al[r][c4+0]=v.x; al[r][c4+1]=v.y; al[r][c4+2]=v.z; al[r][c4+3]=v.w;
        }
        __syncthreads();
        #pragma unroll 4
        for (int e = 0; e < 64; e += 4) {
            const float a0v=al[b][e], a1v=al[b][e+1], a2v=al[b][e+2], a3v=al[b][e+3];
            #pragma unroll
            for (int jj = 0; jj < 4; ++jj) {
                const float4 wq = *(const float4*)&wcat[(size_t)(j0+jj)*1024 + kc*256 + ch*64 + e];
                acc[jj] = fmaf(a0v,wq.x, fmaf(a1v,wq.y, fmaf(a2v,wq.z, fmaf(a3v,wq.w, acc[jj]))));
            }
        }
    }
    #pragma unroll
    for (int jj = 0; jj < 4; ++jj)
        ws[CPART_OFF + ((size_t)kc*NH + j0+jj)*NB + b] = acc[jj];
}

// K5b: sum split-K partials + bias + tanh -> concat_output (bf16 for MFMA k6)
__global__ __launch_bounds__(256) void k5b_concat_fin(
    const float* __restrict__ bcat, float* __restrict__ ws)
{
    const int t = threadIdx.x;
    const int b = t & 63;
    const int j = blockIdx.x * 4 + (t >> 6);
    float v = bcat[j];
    #pragma unroll
    for (int kc = 0; kc < 4; ++kc)
        v += ws[CPART_OFF + ((size_t)kc*NH + j)*NB + b];
    const float e2 = __expf(-2.f * fabsf(v));
    const float th = copysignf((1.f - e2) / (1.f + e2), v);
    unsigned short* ccb = (unsigned short*)(ws + CCB_OFF);
    ccb[b*NH + j] = f2bf(th);
}

// K6: vocab projection via bf16 MFMA. Depth-4 register software-pipeline on the
// wout stream (8 loads in flight/wave) to cover HBM/L3 latency at 3 waves/SIMD.
__global__ __launch_bounds__(128) void k6_mfma(
    const float* __restrict__ wout, const float* __restrict__ bout,
    const unsigned short* __restrict__ ccb, float* __restrict__ out)
{
    const int t = threadIdx.x;
    const int w = t >> 6;
    const int l = t & 63;
    const int lm = l & 15;
    const int kg = l >> 4;
    const int j = blockIdx.x * 32 + w * 16 + lm;
    const int jc = j < NV ? j : NV - 1;
    const float4* wrow4 = (const float4*)(wout + (size_t)jc * NH + kg * 8);
    f32x4 acc0 = {0.f,0.f,0.f,0.f};
    f32x4 acc1 = {0.f,0.f,0.f,0.f};
    f32x4 acc2 = {0.f,0.f,0.f,0.f};
    f32x4 acc3 = {0.f,0.f,0.f,0.f};
    float4 pa[4], pb[4];
    #pragma unroll
    for (int p = 0; p < 4; ++p) {       // prime 4 iterations of wout (8 loads)
        pa[p] = wrow4[p * 8];
        pb[p] = wrow4[p * 8 + 1];
    }
    #pragma unroll
    for (int ks = 0; ks < 16; ++ks) {   // full unroll -> pa/pb indices static
        const float4 w0 = pa[ks & 3];
        const float4 w1 = pb[ks & 3];
        if (ks + 4 < 16) {
            pa[ks & 3] = wrow4[(ks + 4) * 8];
            pb[ks & 3] = wrow4[(ks + 4) * 8 + 1];
        }
        bf16x8 bf;
        bf[0] = (short)f2bf(w0.x); bf[1] = (short)f2bf(w0.y);
        bf[2] = (short)f2bf(w0.z); bf[3] = (short)f2bf(w0.w);
        bf[4] = (short)f2bf(w1.x); bf[5] = (short)f2bf(w1.y);
        bf[6] = (short)f2bf(w1.z); bf[7] = (short)f2bf(w1.w);
        const int ka = ks * 32 + kg * 8;
        const bf16x8 a0 = *(const bf16x8*)&ccb[(0*16 + lm) * NH + ka];
        const bf16x8 a1 = *(const bf16x8*)&ccb[(1*16 + lm) * NH + ka];
        const bf16x8 a2 = *(const bf16x8*)&ccb[(2*16 + lm) * NH + ka];
        const bf16x8 a3 = *(const bf16x8*)&ccb[(3*16 + lm) * NH + ka];
        acc0 = __builtin_amdgcn_mfma_f32_16x16x32_bf16(a0, bf, acc0, 0, 0, 0);
        acc1 = __builtin_amdgcn_mfma_f32_16x16x32_bf16(a1, bf, acc1, 0, 0, 0);
        acc2 = __builtin_amdgcn_mfma_f32_16x16x32_bf16(a2, bf, acc2, 0, 0, 0);
        acc3 = __builtin_amdgcn_mfma_f32_16x16x32_bf16(a3, bf, acc3, 0, 0, 0);
    }
    if (j < NV) {
        const float bj = bout[jc];
        #pragma unroll
        for (int r = 0; r < 4; ++r) {
            out[(size_t)(0*16 + kg*4 + r) * NV + j] = acc0[r] + bj;
            out[(size_t)(1*16 + kg*4 + r) * NV + j] = acc1[r] + bj;
            out[(size_t)(2*16 + kg*4 + r) * NV + j] = acc2[r] + bj;
            out[(size_t)(3*16 + kg*4 + r) * NV + j] = acc3[r] + bj;
        }
    }
}

extern "C" void kernel_launch(void* const* d_in, const int* in_sizes, int n_in,
                              void* d_out, int out_size, void* d_ws, size_t ws_size,
                              hipStream_t stream) {
    (void)in_sizes; (void)n_in; (void)out_size; (void)ws_size;
    const int*   seq  = (const int*)  d_in[0];
    const float* lh   = (const float*)d_in[1];
    const float* enc  = (const float*)d_in[2];
    const float* emb  = (const float*)d_in[3];
    const float* wih  = (const float*)d_in[4];
    const float* whh  = (const float*)d_in[5];
    const float* bih  = (const float*)d_in[6];
    const float* bhh  = (const float*)d_in[7];
    const float* wcat = (const float*)d_in[8];
    const float* bcat = (const float*)d_in[9];
    const float* wout = (const float*)d_in[10];
    const float* bout = (const float*)d_in[11];
    float* out = (float*)d_out;
    float* ws  = (float*)d_ws;

    k1_gru_gemm <<<dim3(96, KSL), 256, 0, stream>>>(seq, lh, emb, wih, whh, ws);
    k2_gates    <<<128, 256, 0, stream>>>(lh, bih, bhh, ws, out);
    k3_attn     <<<2048, 256, 0, stream>>>(enc, ws);
    k4_combine  <<<dim3(64, 4), 256, 0, stream>>>(ws, out);
    k5_concat_gemm<<<dim3(32, 4), 256, 0, stream>>>(wcat, ws);
    k5b_concat_fin<<<128, 256, 0, stream>>>(bcat, ws);
    k6_mfma     <<<1571, 128, 0, stream>>>(wout, bout,
                     (const unsigned short*)(ws + CCB_OFF), out);
}